// Round 2
// baseline (4527.083 us; speedup 1.0000x reference)
//
#include <hip/hip_runtime.h>
#include <hip/hip_cooperative_groups.h>
#include <math.h>

namespace cg = cooperative_groups;

#define B_  32
#define T_  48
#define H_  1024
#define D_  512
#define V_  32000
#define G4  4096   // 4*H

// ---------------------------------------------------------------------------
// Tiled fp32 GEMM #1: x_gates.
//   xg[r = t*B+b][n] = dot(embedding[tok(b,t)], W_ih[n]) + b_ih[n]+b_hh[n]
//   M=1536, N=4096, K=512. 128x128 tile, BK=16, 256 thr, 8x8 microtile (4+4).
// ---------------------------------------------------------------------------
__global__ __launch_bounds__(256)
void gemm_xg(const int* __restrict__ sent_inputs,
             const float* __restrict__ embedding,
             const float* __restrict__ W_ih,
             const float* __restrict__ b_ih,
             const float* __restrict__ b_hh,
             float* __restrict__ xg)
{
    __shared__ float As[16][132];
    __shared__ float Bs[16][132];
    __shared__ int   rowoff[128];

    const int tid = threadIdx.x;
    const int rb  = blockIdx.x * 128;
    const int nb  = blockIdx.y * 128;

    if (tid < 128) {
        int r   = rb + tid;
        int t   = r >> 5;        // r = t*32 + b
        int b   = r & 31;
        int tok = sent_inputs[b * T_ + t];
        rowoff[tid] = tok * D_;
    }
    __syncthreads();

    const int ty = tid >> 4, tx = tid & 15;
    float acc[8][8];
#pragma unroll
    for (int i = 0; i < 8; ++i)
#pragma unroll
        for (int j = 0; j < 8; ++j) acc[i][j] = 0.f;

    for (int it = 0; it < D_ / 16; ++it) {
        const int k0 = it * 16;
        __syncthreads();
#pragma unroll
        for (int j = 0; j < 2; ++j) {
            int i  = tid + j * 256;
            int m  = i >> 2;
            int kk = (i & 3) << 2;
            float4 av = *reinterpret_cast<const float4*>(embedding + rowoff[m] + k0 + kk);
            As[kk+0][m] = av.x; As[kk+1][m] = av.y; As[kk+2][m] = av.z; As[kk+3][m] = av.w;
            float4 bv = *reinterpret_cast<const float4*>(W_ih + (size_t)(nb + m) * D_ + k0 + kk);
            Bs[kk+0][m] = bv.x; Bs[kk+1][m] = bv.y; Bs[kk+2][m] = bv.z; Bs[kk+3][m] = bv.w;
        }
        __syncthreads();
#pragma unroll
        for (int kk = 0; kk < 16; ++kk) {
            float4 a0 = *reinterpret_cast<const float4*>(&As[kk][ty * 4]);
            float4 a1 = *reinterpret_cast<const float4*>(&As[kk][64 + ty * 4]);
            float4 b0 = *reinterpret_cast<const float4*>(&Bs[kk][tx * 4]);
            float4 b1 = *reinterpret_cast<const float4*>(&Bs[kk][64 + tx * 4]);
            float a[8] = {a0.x,a0.y,a0.z,a0.w,a1.x,a1.y,a1.z,a1.w};
            float b[8] = {b0.x,b0.y,b0.z,b0.w,b1.x,b1.y,b1.z,b1.w};
#pragma unroll
            for (int i = 0; i < 8; ++i)
#pragma unroll
                for (int j = 0; j < 8; ++j) acc[i][j] = fmaf(a[i], b[j], acc[i][j]);
        }
    }

    float bias[8];
#pragma unroll
    for (int j = 0; j < 8; ++j) {
        int n = nb + ((j < 4) ? tx * 4 + j : 64 + tx * 4 + (j - 4));
        bias[j] = b_ih[n] + b_hh[n];
    }
#pragma unroll
    for (int i = 0; i < 8; ++i) {
        int m = (i < 4) ? ty * 4 + i : 64 + ty * 4 + (i - 4);
        int r = rb + m;
        float* op = xg + (size_t)r * G4 + nb;
        float4 v0 = make_float4(acc[i][0]+bias[0], acc[i][1]+bias[1],
                                acc[i][2]+bias[2], acc[i][3]+bias[3]);
        float4 v1 = make_float4(acc[i][4]+bias[4], acc[i][5]+bias[5],
                                acc[i][6]+bias[6], acc[i][7]+bias[7]);
        *reinterpret_cast<float4*>(op + tx * 4)      = v0;
        *reinterpret_cast<float4*>(op + 64 + tx * 4) = v1;
    }
}

// ---------------------------------------------------------------------------
// Tiled fp32 GEMM #2: logits. M=1536, N=32000, K=1024. out layout [B,T,V].
// ---------------------------------------------------------------------------
__global__ __launch_bounds__(256)
void gemm_logits(const float* __restrict__ hs,
                 const float* __restrict__ W_out,
                 const float* __restrict__ b_out,
                 float* __restrict__ out)
{
    __shared__ float As[16][132];
    __shared__ float Bs[16][132];
    __shared__ int   rowoff[128];

    const int tid = threadIdx.x;
    const int rb  = blockIdx.x * 128;
    const int nb  = blockIdx.y * 128;

    if (tid < 128) {
        int r = rb + tid;
        int b = r / T_;            // r = b*48 + t
        int t = r - b * T_;
        rowoff[tid] = (t * B_ + b) * H_;
    }
    __syncthreads();

    const int ty = tid >> 4, tx = tid & 15;
    float acc[8][8];
#pragma unroll
    for (int i = 0; i < 8; ++i)
#pragma unroll
        for (int j = 0; j < 8; ++j) acc[i][j] = 0.f;

    for (int it = 0; it < H_ / 16; ++it) {
        const int k0 = it * 16;
        __syncthreads();
#pragma unroll
        for (int j = 0; j < 2; ++j) {
            int i  = tid + j * 256;
            int m  = i >> 2;
            int kk = (i & 3) << 2;
            float4 av = *reinterpret_cast<const float4*>(hs + rowoff[m] + k0 + kk);
            As[kk+0][m] = av.x; As[kk+1][m] = av.y; As[kk+2][m] = av.z; As[kk+3][m] = av.w;
            float4 bv = *reinterpret_cast<const float4*>(W_out + (size_t)(nb + m) * H_ + k0 + kk);
            Bs[kk+0][m] = bv.x; Bs[kk+1][m] = bv.y; Bs[kk+2][m] = bv.z; Bs[kk+3][m] = bv.w;
        }
        __syncthreads();
#pragma unroll
        for (int kk = 0; kk < 16; ++kk) {
            float4 a0 = *reinterpret_cast<const float4*>(&As[kk][ty * 4]);
            float4 a1 = *reinterpret_cast<const float4*>(&As[kk][64 + ty * 4]);
            float4 b0 = *reinterpret_cast<const float4*>(&Bs[kk][tx * 4]);
            float4 b1 = *reinterpret_cast<const float4*>(&Bs[kk][64 + tx * 4]);
            float a[8] = {a0.x,a0.y,a0.z,a0.w,a1.x,a1.y,a1.z,a1.w};
            float b[8] = {b0.x,b0.y,b0.z,b0.w,b1.x,b1.y,b1.z,b1.w};
#pragma unroll
            for (int i = 0; i < 8; ++i)
#pragma unroll
                for (int j = 0; j < 8; ++j) acc[i][j] = fmaf(a[i], b[j], acc[i][j]);
        }
    }

    float bias[8];
#pragma unroll
    for (int j = 0; j < 8; ++j) {
        int n = nb + ((j < 4) ? tx * 4 + j : 64 + tx * 4 + (j - 4));
        bias[j] = b_out[n];
    }
#pragma unroll
    for (int i = 0; i < 8; ++i) {
        int m = (i < 4) ? ty * 4 + i : 64 + ty * 4 + (i - 4);
        int r = rb + m;
        float* op = out + (size_t)r * V_ + nb;
        float4 v0 = make_float4(acc[i][0]+bias[0], acc[i][1]+bias[1],
                                acc[i][2]+bias[2], acc[i][3]+bias[3]);
        float4 v1 = make_float4(acc[i][4]+bias[4], acc[i][5]+bias[5],
                                acc[i][6]+bias[6], acc[i][7]+bias[7]);
        *reinterpret_cast<float4*>(op + tx * 4)      = v0;
        *reinterpret_cast<float4*>(op + 64 + tx * 4) = v1;
    }
}

// ---------------------------------------------------------------------------
// hx0 = hidden_state[b, sent_len[b]-1, :]
// ---------------------------------------------------------------------------
__global__ __launch_bounds__(256)
void lstm_init(const float* __restrict__ hidden_state,
               const int* __restrict__ sent_len,
               float* __restrict__ hx0)
{
    int idx = blockIdx.x * 256 + threadIdx.x;    // 32768 total
    int b = idx >> 10, h = idx & 1023;
    int sl = sent_len[b];
    hx0[idx] = hidden_state[((size_t)b * T_ + (sl - 1)) * H_ + h];
}

// ---------------------------------------------------------------------------
// Fused 48-step LSTM scan, cooperative launch. Grid 256 x 256 threads.
// Block bid owns h-indices h0=bid*4..+3 (16 W_hh gate-rows), staged ONCE in
// LDS as Wl[k][hl][gate] (exactly 64 KB, conflict-free broadcast b128 reads).
// Thread = (b, hl, kh): tid = hl + 4*kh + 8*b. Computes ALL 4 gates for its
// (b, h=h0+hl) over k-half kh*512; __shfl_xor(.,4) merges the two k-halves;
// cx lives in a register; hs[t] doubles as the hx buffer. One grid.sync()
// per step; no __syncthreads in the step body.
// ---------------------------------------------------------------------------
__global__ __launch_bounds__(256, 1)
void lstm_scan(const float* __restrict__ W_hh,
               const float* __restrict__ xg,
               const float* __restrict__ hx0,
               float* __restrict__ hs)
{
    __shared__ float Wl[16 * 1024];   // [k][hl][g] -> ((k*4+hl)*4+g), 64 KB

    const int tid = threadIdx.x;
    const int h0  = blockIdx.x * 4;

    // ---- stage W_hh tile (once): row (g,hl) is contiguous in k, coalesced
#pragma unroll
    for (int r = 0; r < 16; ++r) {
        int g = r >> 2, hl = r & 3;
        const float4* src = reinterpret_cast<const float4*>(
            W_hh + (size_t)(g * H_ + h0 + hl) * H_);
        float4 v = src[tid];             // float4 index tid -> k = 4*tid
        int k = tid * 4;
        Wl[((k + 0) * 4 + hl) * 4 + g] = v.x;
        Wl[((k + 1) * 4 + hl) * 4 + g] = v.y;
        Wl[((k + 2) * 4 + hl) * 4 + g] = v.z;
        Wl[((k + 3) * 4 + hl) * 4 + g] = v.w;
    }
    __syncthreads();

    const int hl    = tid & 3;
    const int kh    = (tid >> 2) & 1;
    const int b     = tid >> 3;          // 0..31
    const int h     = h0 + hl;
    const int kbase = kh * (H_ / 2);

    const float4* W4 = reinterpret_cast<const float4*>(Wl);  // idx = k*4+hl

    float c = 0.f;
    cg::grid_group grid = cg::this_grid();

    for (int t = 0; t < T_; ++t) {
        const float* hx = (t == 0) ? (hx0 + b * H_)
                                   : (hs + (size_t)(t - 1) * B_ * H_ + b * H_);
        const float4* hx4 = reinterpret_cast<const float4*>(hx + kbase);

        float ai = 0.f, af = 0.f, ag = 0.f, ao = 0.f;
#pragma unroll 4
        for (int kq = 0; kq < H_ / 8; ++kq) {     // 128 iters of 4 k each
            float4 hv = hx4[kq];
            int kf = (kbase + kq * 4) * 4 + hl;   // float4 index for k, i=0
            float4 w0 = W4[kf];
            float4 w1 = W4[kf + 4];
            float4 w2 = W4[kf + 8];
            float4 w3 = W4[kf + 12];
            ai = fmaf(hv.x, w0.x, ai); af = fmaf(hv.x, w0.y, af);
            ag = fmaf(hv.x, w0.z, ag); ao = fmaf(hv.x, w0.w, ao);
            ai = fmaf(hv.y, w1.x, ai); af = fmaf(hv.y, w1.y, af);
            ag = fmaf(hv.y, w1.z, ag); ao = fmaf(hv.y, w1.w, ao);
            ai = fmaf(hv.z, w2.x, ai); af = fmaf(hv.z, w2.y, af);
            ag = fmaf(hv.z, w2.z, ag); ao = fmaf(hv.z, w2.w, ao);
            ai = fmaf(hv.w, w3.x, ai); af = fmaf(hv.w, w3.y, af);
            ag = fmaf(hv.w, w3.z, ag); ao = fmaf(hv.w, w3.w, ao);
        }
        // merge the two k-halves (partner lane differs in bit 2 = kh)
        ai += __shfl_xor(ai, 4);
        af += __shfl_xor(af, 4);
        ag += __shfl_xor(ag, 4);
        ao += __shfl_xor(ao, 4);

        const float* xgt = xg + (size_t)t * B_ * G4 + b * G4;
        ai += xgt[0 * H_ + h];
        af += xgt[1 * H_ + h];
        ag += xgt[2 * H_ + h];
        ao += xgt[3 * H_ + h];

        float is = 1.f / (1.f + expf(-ai));
        float fs = 1.f / (1.f + expf(-af));
        float gt = tanhf(ag);
        float os = 1.f / (1.f + expf(-ao));
        c = fs * c + is * gt;                    // identical in both kh lanes
        float hn = os * tanhf(c);
        if (kh == 0)
            hs[(size_t)t * B_ * H_ + b * H_ + h] = hn;

        __threadfence();
        grid.sync();
    }
}

// ---------------------------------------------------------------------------
// Row-wise argmax over V=32000; lowest index wins ties.
// ---------------------------------------------------------------------------
__global__ __launch_bounds__(256)
void argmax_k(const float* __restrict__ logits, float* __restrict__ outi)
{
    __shared__ float sv[256];
    __shared__ int   si[256];
    int r = blockIdx.x;
    const float* row = logits + (size_t)r * V_;
    float best = -INFINITY;
    int   bi   = 0;
    for (int v = threadIdx.x; v < V_; v += 256) {
        float x = row[v];
        if (x > best) { best = x; bi = v; }
    }
    sv[threadIdx.x] = best; si[threadIdx.x] = bi;
    __syncthreads();
    for (int s = 128; s > 0; s >>= 1) {
        if (threadIdx.x < s) {
            float ov = sv[threadIdx.x + s]; int oi = si[threadIdx.x + s];
            if (ov > sv[threadIdx.x] ||
                (ov == sv[threadIdx.x] && oi < si[threadIdx.x])) {
                sv[threadIdx.x] = ov; si[threadIdx.x] = oi;
            }
        }
        __syncthreads();
    }
    if (threadIdx.x == 0) outi[r] = (float)si[0];
}

// ---------------------------------------------------------------------------
extern "C" void kernel_launch(void* const* d_in, const int* in_sizes, int n_in,
                              void* d_out, int out_size, void* d_ws, size_t ws_size,
                              hipStream_t stream)
{
    const int*   sent_inputs  = (const int*)  d_in[0];
    const float* hidden_state = (const float*)d_in[1];
    const int*   sent_len     = (const int*)  d_in[2];
    const float* embedding    = (const float*)d_in[4];
    const float* W_ih         = (const float*)d_in[5];
    const float* W_hh         = (const float*)d_in[6];
    const float* b_ih         = (const float*)d_in[7];
    const float* b_hh         = (const float*)d_in[8];
    const float* W_out        = (const float*)d_in[9];
    const float* b_out        = (const float*)d_in[10];
    float* out = (float*)d_out;

    // workspace layout (floats): xg | hs | hx0
    float* ws  = (float*)d_ws;
    float* xg  = ws;                               // T*B*4096
    float* hs  = xg  + (size_t)T_ * B_ * G4;       // T*B*H
    float* hx0 = hs  + (size_t)T_ * B_ * H_;       // B*H

    dim3 blk(256);
    gemm_xg<<<dim3(12, 32), blk, 0, stream>>>(sent_inputs, embedding, W_ih, b_ih, b_hh, xg);
    lstm_init<<<dim3(128), blk, 0, stream>>>(hidden_state, sent_len, hx0);

    void* args[] = { (void*)&W_hh, (void*)&xg, (void*)&hx0, (void*)&hs };
    hipLaunchCooperativeKernel((void*)lstm_scan, dim3(256), dim3(256), args, 0, stream);

    gemm_logits<<<dim3(12, 250), blk, 0, stream>>>(hs, W_out, b_out, out);
    argmax_k<<<dim3(B_ * T_), blk, 0, stream>>>(out, out + (size_t)B_ * T_ * V_);
}